// Round 15
// baseline (561.956 us; speedup 1.0000x reference)
//
#include <hip/hip_runtime.h>

#define RANK   64
#define VOCAB  32768
#define BATCH  2048
#define SEQLEN 256

typedef __attribute__((ext_vector_type(4))) unsigned int uint4v;

// ws layout (unchanged from r10):
//   region A (u10 data): per token v, 5 chunks x 1KB (5120B, stride 320 uint4v).
//     chunk c, lane s holds dwords D[4c..4c+3] of lane s's 20-dword blob.
//     Group gi (entries r=16gi..16gi+15) packed LSB-first into D[5gi..5gi+4].
//     entry (r,s) of matrix v: M[r][s] = scale[v][r] * u10.
//   region B (scales): f32 ws_sc[v][r], 256 B per token.
#define WS_DATA_BYTES ((size_t)VOCAB * 5120)
#define WS_SC_BYTES   ((size_t)VOCAB * 256)

// ---------------------------------------------------------------------------
// Kernel 1: squash+quantize u10 (proven r10-r14, unchanged).
// ---------------------------------------------------------------------------
__global__ __launch_bounds__(64) void squash10_kernel(const float* __restrict__ core,
                                                      unsigned int* __restrict__ wsd,
                                                      float* __restrict__ wssc) {
    __shared__ float tsq[64 * 65];
    __shared__ float tinv[64];

    const int v = blockIdx.x;
    const int s = threadIdx.x;

    float sq[64];
#pragma unroll
    for (int r = 0; r < 64; ++r) {
        float c = __builtin_nontemporal_load(&core[((size_t)r * VOCAB + v) * RANK + s]);
        sq[r] = c * c;
    }
#pragma unroll
    for (int r = 0; r < 64; ++r) tsq[r * 65 + s] = sq[r];
    __syncthreads();

    float mx = 0.f;
#pragma unroll
    for (int q = 0; q < 64; ++q) mx = fmaxf(mx, tsq[s * 65 + q]);
    float scale = mx * (1.0f / 1023.0f);
    float inv   = (mx > 0.f) ? (1023.0f / mx) : 0.f;
    wssc[(size_t)v * 64 + s] = scale;
    tinv[s] = inv;
    __syncthreads();

    unsigned int D[20];
#pragma unroll
    for (int gi = 0; gi < 4; ++gi) {
        unsigned int e[16];
#pragma unroll
        for (int q = 0; q < 16; ++q) {
            float qq = sq[16 * gi + q] * tinv[16 * gi + q];
            unsigned int u = (unsigned int)(qq + 0.5f);
            e[q] = (u > 1023u) ? 1023u : u;
        }
        D[5 * gi + 0] = e[0] | (e[1] << 10) | (e[2] << 20) | (e[3] << 30);
        D[5 * gi + 1] = (e[3] >> 2) | (e[4] << 8) | (e[5] << 18) | (e[6] << 28);
        D[5 * gi + 2] = (e[6] >> 4) | (e[7] << 6) | (e[8] << 16) | (e[9] << 26);
        D[5 * gi + 3] = (e[9] >> 6) | (e[10] << 4) | (e[11] << 14) | (e[12] << 24);
        D[5 * gi + 4] = (e[12] >> 8) | (e[13] << 2) | (e[14] << 12) | (e[15] << 22);
    }
    uint4v* dst = (uint4v*)wsd;
#pragma unroll
    for (int c = 0; c < 5; ++c) {
        uint4v w;
        w[0] = D[4 * c + 0]; w[1] = D[4 * c + 1];
        w[2] = D[4 * c + 2]; w[3] = D[4 * c + 3];
        dst[((size_t)v * 5 + c) * 64 + s] = w;
    }
}

// ---------------------------------------------------------------------------
// Kernel 2: r12 structure + scales kept in 3 rotating registers (no LDS
// round-trip for the scale; ls is computable at cycle 0 of consume).
// Per step s (position j = s%3 in the unrolled body):
//   consume(slot j, Sc_j); ds_write slot (s+2)%3 from data regs (step s+2's
//   data, loaded last iter); load step s+3 -> data regs + Sc_j (consumed at
//   s+3, same body position). sched_barrier(0) pins the 3-phase order so
//   loads can't sink (proven r12). Single wave per block: race-free.
// ---------------------------------------------------------------------------
__global__ __launch_bounds__(64) void mps_u10_reg_kernel(const int* __restrict__ y,
                                                         const float* __restrict__ alpha,
                                                         const float* __restrict__ beta,
                                                         const unsigned int* __restrict__ wsd,
                                                         const float* __restrict__ wssc,
                                                         float* __restrict__ out) {
    __shared__ uint4v sdat[3][5][64]; // 15360 B

    const int b    = blockIdx.x;
    const int lane = threadIdx.x;
    const int* yrow = y + (size_t)b * SEQLEN;

    int yr0 = yrow[0 * 64 + lane];
    int yr1 = yrow[1 * 64 + lane];
    int yr2 = yrow[2 * 64 + lane];
    int yr3 = yrow[3 * 64 + lane];

    float a  = alpha[lane];
    float bb = beta[lane];
    float l  = a * a;
    float b2 = bb * bb;

    const uint4v* wsd4 = (const uint4v*)wsd;

    // one live data staging set + 3 rotating scale regs
    uint4v R0, R1, R2, R3, R4;
    float  Sc0, Sc1, Sc2;

#define LOADDATA(KK, SCREG)                                                \
    do {                                                                   \
        int kk_ = (KK);                                                    \
        int c_  = kk_ >> 6;                                                \
        int yy  = (c_ == 0) ? yr0 : (c_ == 1) ? yr1 : (c_ == 2) ? yr2 : yr3; \
        int tok = __builtin_amdgcn_readlane(yy, kk_ & 63);                 \
        const uint4v* gp = wsd4 + (size_t)tok * 320 + lane;                \
        R0 = gp[0 * 64];                                                   \
        R1 = gp[1 * 64];                                                   \
        R2 = gp[2 * 64];                                                   \
        R3 = gp[3 * 64];                                                   \
        R4 = gp[4 * 64];                                                   \
        SCREG = wssc[(size_t)tok * 64 + lane];                             \
    } while (0)

    auto writeslot = [&](int slot) {
        sdat[slot][0][lane] = R0;
        sdat[slot][1][lane] = R1;
        sdat[slot][2][lane] = R2;
        sdat[slot][3][lane] = R3;
        sdat[slot][4][lane] = R4;
    };

    auto consume = [&](int slot, float sc) {
        float ls = l * sc; // no LDS dependency at the head of the chain
        unsigned int D[20];
#pragma unroll
        for (int c = 0; c < 5; ++c) {
            uint4v d = sdat[slot][c][lane]; // ds_read_b128
            D[4 * c + 0] = d[0]; D[4 * c + 1] = d[1];
            D[4 * c + 2] = d[2]; D[4 * c + 3] = d[3];
        }
        float acc0 = 0.f, acc1 = 0.f, acc2 = 0.f, acc3 = 0.f;
#pragma unroll
        for (int gi = 0; gi < 4; ++gi) {
            unsigned int d0 = D[5 * gi + 0], d1 = D[5 * gi + 1],
                         d2 = D[5 * gi + 2], d3 = D[5 * gi + 3],
                         d4 = D[5 * gi + 4];
            unsigned int ee[16];
            ee[0]  = d0 & 1023u;
            ee[1]  = (d0 >> 10) & 1023u;
            ee[2]  = (d0 >> 20) & 1023u;
            ee[3]  = ((d0 >> 30) | (d1 << 2)) & 1023u;
            ee[4]  = (d1 >> 8) & 1023u;
            ee[5]  = (d1 >> 18) & 1023u;
            ee[6]  = ((d1 >> 28) | (d2 << 4)) & 1023u;
            ee[7]  = (d2 >> 6) & 1023u;
            ee[8]  = (d2 >> 16) & 1023u;
            ee[9]  = ((d2 >> 26) | (d3 << 6)) & 1023u;
            ee[10] = (d3 >> 4) & 1023u;
            ee[11] = (d3 >> 14) & 1023u;
            ee[12] = ((d3 >> 24) | (d4 << 8)) & 1023u;
            ee[13] = (d4 >> 2) & 1023u;
            ee[14] = (d4 >> 12) & 1023u;
            ee[15] = d4 >> 22;
#pragma unroll
            for (int q = 0; q < 16; ++q) {
                const int r = 16 * gi + q;
                float lr = __uint_as_float(
                    __builtin_amdgcn_readlane(__float_as_uint(ls), r));
                float mv = (float)ee[q];
                if ((q & 3) == 0)      acc0 = fmaf(lr, mv, acc0);
                else if ((q & 3) == 1) acc1 = fmaf(lr, mv, acc1);
                else if ((q & 3) == 2) acc2 = fmaf(lr, mv, acc2);
                else                   acc3 = fmaf(lr, mv, acc3);
            }
        }
        l = (acc0 + acc1) + (acc2 + acc3);
    };

    // prologue: slots 0,1 filled (scales for steps 0,1 in Sc0,Sc1);
    // data regs + Sc2 hold step 2
    LOADDATA(0, Sc0); writeslot(0);
    LOADDATA(1, Sc1); writeslot(1);
    LOADDATA(2, Sc2);
    __builtin_amdgcn_sched_barrier(0);

    // Step s at body position j=s%3: consume(slot j, Sc_j); write slot
    // (s+2)%3 from regs; load step s+3 (scale -> Sc_j, consumed at s+3).
#define STEP(S, CSLOT, WSLOT, SCREG)                                       \
    do {                                                                   \
        consume((CSLOT), SCREG);                                           \
        __builtin_amdgcn_sched_barrier(0);                                 \
        writeslot((WSLOT)); /* regs hold step (S)+2 */                     \
        __builtin_amdgcn_sched_barrier(0);                                 \
        int kk = (S) + 3; kk = (kk > SEQLEN - 1) ? (SEQLEN - 1) : kk;      \
        LOADDATA(kk, SCREG);                                               \
        __builtin_amdgcn_sched_barrier(0);                                 \
    } while (0)

#pragma unroll 1
    for (int t3 = 0; t3 < 85; ++t3) { // steps 0..254
        int s0 = 3 * t3;
        STEP(s0 + 0, 0, 2, Sc0);
        STEP(s0 + 1, 1, 0, Sc1);
        STEP(s0 + 2, 2, 1, Sc2);
    }
    // epilogue: step 255 (255%3==0 -> slot 0, written at s=253; scale Sc0
    // loaded at s=252 with kk=255)
    consume(0, Sc0);
#undef STEP
#undef LOADDATA

    float v = l * b2;
#pragma unroll
    for (int off = 32; off > 0; off >>= 1) v += __shfl_xor(v, off, 64);
    if (lane == 0) out[b] = v;
}

// ---------------------------------------------------------------------------
// Fallback (exact f32, direct gather from core) if ws is too small.
// ---------------------------------------------------------------------------
__global__ __launch_bounds__(256) void mps_f32_kernel(const int* __restrict__ y,
                                                      const float* __restrict__ alpha,
                                                      const float* __restrict__ beta,
                                                      const float* __restrict__ core,
                                                      float* __restrict__ out) {
    int b    = (blockIdx.x * 256 + threadIdx.x) >> 6;
    int lane = threadIdx.x & 63;
    const int* yrow = y + (size_t)b * SEQLEN;

    float a = alpha[lane];
    float l = a * a;

#pragma unroll 1
    for (int t = 0; t < SEQLEN; ++t) {
        int tok = __builtin_amdgcn_readfirstlane(yrow[t]);
        const float* p = core + (size_t)tok * RANK + lane;
        float acc[4] = {0.f, 0.f, 0.f, 0.f};
#pragma unroll
        for (int r = 0; r < 64; ++r) {
            float m  = p[(size_t)r * (VOCAB * RANK)];
            float lr = __uint_as_float(
                __builtin_amdgcn_readlane(__float_as_uint(l), r));
            acc[r & 3] = fmaf(lr, m * m, acc[r & 3]);
        }
        l = (acc[0] + acc[1]) + (acc[2] + acc[3]);
    }

    float bb = beta[lane];
    float v  = l * bb * bb;
#pragma unroll
    for (int off = 32; off > 0; off >>= 1) v += __shfl_xor(v, off, 64);
    if (lane == 0) out[b] = v;
}

extern "C" void kernel_launch(void* const* d_in, const int* in_sizes, int n_in,
                              void* d_out, int out_size, void* d_ws, size_t ws_size,
                              hipStream_t stream) {
    const int*   y     = (const int*)d_in[0];
    const float* alpha = (const float*)d_in[1];
    const float* beta  = (const float*)d_in[2];
    const float* core  = (const float*)d_in[3];
    float*       out   = (float*)d_out;

    const size_t need = WS_DATA_BYTES + WS_SC_BYTES; // 168 MiB

    if (ws_size >= need) {
        unsigned int* wsd  = (unsigned int*)d_ws;
        float*        wssc = (float*)((char*)d_ws + WS_DATA_BYTES);
        squash10_kernel<<<VOCAB, 64, 0, stream>>>(core, wsd, wssc);
        mps_u10_reg_kernel<<<BATCH, 64, 0, stream>>>(y, alpha, beta, wsd, wssc, out);
    } else {
        mps_f32_kernel<<<(BATCH * 64) / 256, 256, 0, stream>>>(
            y, alpha, beta, core, out);
    }
}

// Round 16
// 536.086 us; speedup vs baseline: 1.0483x; 1.0483x over previous
//
#include <hip/hip_runtime.h>

#define RANK   64
#define VOCAB  32768
#define BATCH  2048
#define SEQLEN 256

typedef __attribute__((ext_vector_type(4))) unsigned int uint4v;

// ws layout (proven r10-r14):
//   region A (u10 data): per token v, 5 chunks x 1KB (5120B, stride 320 uint4v).
//     chunk c, lane s holds dwords D[4c..4c+3] of lane s's 20-dword blob.
//     Group gi (entries r=16gi..16gi+15) packed LSB-first into D[5gi..5gi+4].
//     entry (r,s) of matrix v: M[r][s] = scale[v][r] * u10.
//   region B (scales): f32 ws_sc[v][r], 256 B per token.
#define WS_DATA_BYTES ((size_t)VOCAB * 5120)
#define WS_SC_BYTES   ((size_t)VOCAB * 256)

// ---------------------------------------------------------------------------
// Kernel 1: squash+quantize u10 (proven r10-r14).
// ---------------------------------------------------------------------------
__global__ __launch_bounds__(64) void squash10_kernel(const float* __restrict__ core,
                                                      unsigned int* __restrict__ wsd,
                                                      float* __restrict__ wssc) {
    __shared__ float tsq[64 * 65];
    __shared__ float tinv[64];

    const int v = blockIdx.x;
    const int s = threadIdx.x;

    float sq[64];
#pragma unroll
    for (int r = 0; r < 64; ++r) {
        float c = __builtin_nontemporal_load(&core[((size_t)r * VOCAB + v) * RANK + s]);
        sq[r] = c * c;
    }
#pragma unroll
    for (int r = 0; r < 64; ++r) tsq[r * 65 + s] = sq[r];
    __syncthreads();

    float mx = 0.f;
#pragma unroll
    for (int q = 0; q < 64; ++q) mx = fmaxf(mx, tsq[s * 65 + q]);
    float scale = mx * (1.0f / 1023.0f);
    float inv   = (mx > 0.f) ? (1023.0f / mx) : 0.f;
    wssc[(size_t)v * 64 + s] = scale;
    tinv[s] = inv;
    __syncthreads();

    unsigned int D[20];
#pragma unroll
    for (int gi = 0; gi < 4; ++gi) {
        unsigned int e[16];
#pragma unroll
        for (int q = 0; q < 16; ++q) {
            float qq = sq[16 * gi + q] * tinv[16 * gi + q];
            unsigned int u = (unsigned int)(qq + 0.5f);
            e[q] = (u > 1023u) ? 1023u : u;
        }
        D[5 * gi + 0] = e[0] | (e[1] << 10) | (e[2] << 20) | (e[3] << 30);
        D[5 * gi + 1] = (e[3] >> 2) | (e[4] << 8) | (e[5] << 18) | (e[6] << 28);
        D[5 * gi + 2] = (e[6] >> 4) | (e[7] << 6) | (e[8] << 16) | (e[9] << 26);
        D[5 * gi + 3] = (e[9] >> 6) | (e[10] << 4) | (e[11] << 14) | (e[12] << 24);
        D[5 * gi + 4] = (e[12] >> 8) | (e[13] << 2) | (e[14] << 12) | (e[15] << 22);
    }
    uint4v* dst = (uint4v*)wsd;
#pragma unroll
    for (int c = 0; c < 5; ++c) {
        uint4v w;
        w[0] = D[4 * c + 0]; w[1] = D[4 * c + 1];
        w[2] = D[4 * c + 2]; w[3] = D[4 * c + 3];
        dst[((size_t)v * 5 + c) * 64 + s] = w;
    }
}

// ---------------------------------------------------------------------------
// Kernel 2 (r12 champion, twice-reproduced at 540.0/537.5 us total):
// reg-staged pipeline (T14). Per step s: consume(slot s%3); ds_write slot
// (s+2)%3 from regs (step s+2's data, loaded last iter); load step s+3 ->
// regs. Single wave per block: no inter-wave hazards; compiler inserts
// counted vmcnt for the ds_write operands (correct by construction).
// sched_barrier(0) pins the 3-phase order. One live reg set.
// ---------------------------------------------------------------------------
__global__ __launch_bounds__(64) void mps_u10_reg_kernel(const int* __restrict__ y,
                                                         const float* __restrict__ alpha,
                                                         const float* __restrict__ beta,
                                                         const unsigned int* __restrict__ wsd,
                                                         const float* __restrict__ wssc,
                                                         float* __restrict__ out) {
    __shared__ uint4v sdat[3][5][64]; // 15360 B
    __shared__ float  ssc[3][64];     // 768 B

    const int b    = blockIdx.x;
    const int lane = threadIdx.x;
    const int* yrow = y + (size_t)b * SEQLEN;

    int yr0 = yrow[0 * 64 + lane];
    int yr1 = yrow[1 * 64 + lane];
    int yr2 = yrow[2 * 64 + lane];
    int yr3 = yrow[3 * 64 + lane];

    float a  = alpha[lane];
    float bb = beta[lane];
    float l  = a * a;
    float b2 = bb * bb;

    const uint4v* wsd4 = (const uint4v*)wsd;

    // one live staging set: 5 x uint4v + scale
    uint4v R0, R1, R2, R3, R4;
    float  Rs;

    auto loadregs = [&](int kk) {
        int c_  = kk >> 6;
        int yy  = (c_ == 0) ? yr0 : (c_ == 1) ? yr1 : (c_ == 2) ? yr2 : yr3;
        int tok = __builtin_amdgcn_readlane(yy, kk & 63);
        const uint4v* gp = wsd4 + (size_t)tok * 320 + lane;
        R0 = gp[0 * 64];
        R1 = gp[1 * 64];
        R2 = gp[2 * 64];
        R3 = gp[3 * 64];
        R4 = gp[4 * 64];
        Rs = wssc[(size_t)tok * 64 + lane];
    };

    auto writeslot = [&](int slot) {
        sdat[slot][0][lane] = R0;
        sdat[slot][1][lane] = R1;
        sdat[slot][2][lane] = R2;
        sdat[slot][3][lane] = R3;
        sdat[slot][4][lane] = R4;
        ssc[slot][lane]     = Rs;
    };

    auto consume = [&](int slot) {
        float ls = l * ssc[slot][lane];
        unsigned int D[20];
#pragma unroll
        for (int c = 0; c < 5; ++c) {
            uint4v d = sdat[slot][c][lane]; // ds_read_b128
            D[4 * c + 0] = d[0]; D[4 * c + 1] = d[1];
            D[4 * c + 2] = d[2]; D[4 * c + 3] = d[3];
        }
        float acc0 = 0.f, acc1 = 0.f, acc2 = 0.f, acc3 = 0.f;
#pragma unroll
        for (int gi = 0; gi < 4; ++gi) {
            unsigned int d0 = D[5 * gi + 0], d1 = D[5 * gi + 1],
                         d2 = D[5 * gi + 2], d3 = D[5 * gi + 3],
                         d4 = D[5 * gi + 4];
            unsigned int ee[16];
            ee[0]  = d0 & 1023u;
            ee[1]  = (d0 >> 10) & 1023u;
            ee[2]  = (d0 >> 20) & 1023u;
            ee[3]  = ((d0 >> 30) | (d1 << 2)) & 1023u;
            ee[4]  = (d1 >> 8) & 1023u;
            ee[5]  = (d1 >> 18) & 1023u;
            ee[6]  = ((d1 >> 28) | (d2 << 4)) & 1023u;
            ee[7]  = (d2 >> 6) & 1023u;
            ee[8]  = (d2 >> 16) & 1023u;
            ee[9]  = ((d2 >> 26) | (d3 << 6)) & 1023u;
            ee[10] = (d3 >> 4) & 1023u;
            ee[11] = (d3 >> 14) & 1023u;
            ee[12] = ((d3 >> 24) | (d4 << 8)) & 1023u;
            ee[13] = (d4 >> 2) & 1023u;
            ee[14] = (d4 >> 12) & 1023u;
            ee[15] = d4 >> 22;
#pragma unroll
            for (int q = 0; q < 16; ++q) {
                const int r = 16 * gi + q;
                float lr = __uint_as_float(
                    __builtin_amdgcn_readlane(__float_as_uint(ls), r));
                float mv = (float)ee[q];
                if ((q & 3) == 0)      acc0 = fmaf(lr, mv, acc0);
                else if ((q & 3) == 1) acc1 = fmaf(lr, mv, acc1);
                else if ((q & 3) == 2) acc2 = fmaf(lr, mv, acc2);
                else                   acc3 = fmaf(lr, mv, acc3);
            }
        }
        l = (acc0 + acc1) + (acc2 + acc3);
    };

    // prologue: slots 0,1 filled; regs hold step 2
    loadregs(0); writeslot(0);
    loadregs(1); writeslot(1);
    loadregs(2);
    __builtin_amdgcn_sched_barrier(0);

#define STEP(S, CSLOT, WSLOT)                                              \
    do {                                                                   \
        consume((CSLOT));                                                  \
        __builtin_amdgcn_sched_barrier(0);                                 \
        writeslot((WSLOT)); /* regs hold step (S)+2 */                     \
        __builtin_amdgcn_sched_barrier(0);                                 \
        int kk = (S) + 3; kk = (kk > SEQLEN - 1) ? (SEQLEN - 1) : kk;      \
        loadregs(kk);                                                      \
        __builtin_amdgcn_sched_barrier(0);                                 \
    } while (0)

#pragma unroll 1
    for (int t3 = 0; t3 < 85; ++t3) { // steps 0..254
        int s0 = 3 * t3;
        STEP(s0 + 0, 0, 2);
        STEP(s0 + 1, 1, 0);
        STEP(s0 + 2, 2, 1);
    }
    // epilogue: step 255 (255%3==0 -> slot 0, written at s=253)
    consume(0);
#undef STEP

    float v = l * b2;
#pragma unroll
    for (int off = 32; off > 0; off >>= 1) v += __shfl_xor(v, off, 64);
    if (lane == 0) out[b] = v;
}

// ---------------------------------------------------------------------------
// Fallback (exact f32, direct gather from core) if ws is too small.
// ---------------------------------------------------------------------------
__global__ __launch_bounds__(256) void mps_f32_kernel(const int* __restrict__ y,
                                                      const float* __restrict__ alpha,
                                                      const float* __restrict__ beta,
                                                      const float* __restrict__ core,
                                                      float* __restrict__ out) {
    int b    = (blockIdx.x * 256 + threadIdx.x) >> 6;
    int lane = threadIdx.x & 63;
    const int* yrow = y + (size_t)b * SEQLEN;

    float a = alpha[lane];
    float l = a * a;

#pragma unroll 1
    for (int t = 0; t < SEQLEN; ++t) {
        int tok = __builtin_amdgcn_readfirstlane(yrow[t]);
        const float* p = core + (size_t)tok * RANK + lane;
        float acc[4] = {0.f, 0.f, 0.f, 0.f};
#pragma unroll
        for (int r = 0; r < 64; ++r) {
            float m  = p[(size_t)r * (VOCAB * RANK)];
            float lr = __uint_as_float(
                __builtin_amdgcn_readlane(__float_as_uint(l), r));
            acc[r & 3] = fmaf(lr, m * m, acc[r & 3]);
        }
        l = (acc[0] + acc[1]) + (acc[2] + acc[3]);
    }

    float bb = beta[lane];
    float v  = l * bb * bb;
#pragma unroll
    for (int off = 32; off > 0; off >>= 1) v += __shfl_xor(v, off, 64);
    if (lane == 0) out[b] = v;
}

extern "C" void kernel_launch(void* const* d_in, const int* in_sizes, int n_in,
                              void* d_out, int out_size, void* d_ws, size_t ws_size,
                              hipStream_t stream) {
    const int*   y     = (const int*)d_in[0];
    const float* alpha = (const float*)d_in[1];
    const float* beta  = (const float*)d_in[2];
    const float* core  = (const float*)d_in[3];
    float*       out   = (float*)d_out;

    const size_t need = WS_DATA_BYTES + WS_SC_BYTES; // 168 MiB

    if (ws_size >= need) {
        unsigned int* wsd  = (unsigned int*)d_ws;
        float*        wssc = (float*)((char*)d_ws + WS_DATA_BYTES);
        squash10_kernel<<<VOCAB, 64, 0, stream>>>(core, wsd, wssc);
        mps_u10_reg_kernel<<<BATCH, 64, 0, stream>>>(y, alpha, beta, wsd, wssc, out);
    } else {
        mps_f32_kernel<<<(BATCH * 64) / 256, 256, 0, stream>>>(
            y, alpha, beta, core, out);
    }
}